// Round 4
// baseline (433.014 us; speedup 1.0000x reference)
//
#include <hip/hip_runtime.h>
#include <math.h>

// Problem constants (fixed by the reference)
#define BB 256
#define TT 512
#define DD 128
#define HH 128
#define GG 512   // 4*H
#define OO 64

typedef _Float16 half8 __attribute__((ext_vector_type(8)));
typedef float    f32x4 __attribute__((ext_vector_type(4)));

// ---------------------------------------------------------------------------
// Fast activations (fp32; threshold 5.6e-3, plenty of headroom)
// ---------------------------------------------------------------------------
__device__ __forceinline__ float sigmoid_fast(float x) {
    return 1.0f / (1.0f + __expf(-x));
}
__device__ __forceinline__ float tanh_fast(float x) {
    float ax = fabsf(x);
    float e = __expf(2.0f * ax);
    float t = 1.0f - 2.0f / (e + 1.0f);
    return copysignf(t, x);
}

// ---------------------------------------------------------------------------
// Kernel 1: xg[t][g] = dot(x[255,t,:], W_ih[g,:]) + b_ih[g] + b_hh[g]
// Only batch 255 matters: y.reshape(T,B,O)[-1] -> flat rows (b=255, t>=256),
// and b=255's scan needs all t. grid = T, block = 512.
// ---------------------------------------------------------------------------
__global__ __launch_bounds__(512) void xg_kernel(
    const float* __restrict__ x,
    const float* __restrict__ W_ih,
    const float* __restrict__ b_ih,
    const float* __restrict__ b_hh,
    float* __restrict__ xg)
{
    const int t = blockIdx.x;
    const int g = threadIdx.x;

    __shared__ __align__(16) float xs[DD];
    if (g < DD) xs[g] = x[(255 * TT + t) * DD + g];
    __syncthreads();

    const float4* __restrict__ wrow = (const float4*)(W_ih + g * DD);
    const float4* __restrict__ xv   = (const float4*)xs;

    float a0 = 0.f, a1 = 0.f, a2 = 0.f, a3 = 0.f;
#pragma unroll
    for (int i = 0; i < DD / 4; i += 4) {
        float4 w0 = wrow[i + 0], w1 = wrow[i + 1], w2 = wrow[i + 2], w3 = wrow[i + 3];
        float4 h0 = xv[i + 0],  h1 = xv[i + 1],  h2 = xv[i + 2],  h3 = xv[i + 3];
        a0 += w0.x * h0.x + w0.y * h0.y + w0.z * h0.z + w0.w * h0.w;
        a1 += w1.x * h1.x + w1.y * h1.y + w1.z * h1.z + w1.w * h1.w;
        a2 += w2.x * h2.x + w2.y * h2.y + w2.z * h2.z + w2.w * h2.w;
        a3 += w3.x * h3.x + w3.y * h3.y + w3.z * h3.z + w3.w * h3.w;
    }
    xg[t * GG + g] = (a0 + a1) + (a2 + a3) + b_ih[g] + b_hh[g];
}

// ---------------------------------------------------------------------------
// Kernel 2: MFMA LSTM scan (batch 255). 1 block, 256 threads = 4 waves.
//
// Per step: pre[g] = xg[t][g] + h . W_hh[g,:]  via v_mfma_f32_16x16x32_f16.
//   - A-frag: h replicated across all 16 rows (every C row = the matvec).
//   - B-frag: wave w owns hidden slice [32w,32w+32) for ALL 4 gate types ->
//     i,f,g,o for hidden j land in the same lane; update is cross-lane-free.
//   - Weights: 32 named half8 SSA values, converted f32->f16 in the prologue.
//
// OCCUPANCY PIN (the round-2/3 failure): __launch_bounds__(256,1) only sets a
// MINIMUM waves/EU; the scheduler still targets high occupancy and sinks the
// loop-invariant weight loads back into the loop (VGPR=108, 128 KB/step L2
// re-reads). amdgpu_waves_per_eu(1,1) caps the occupancy target at 1 wave/EU
// (we have exactly 4 waves on 1 CU -> nothing lost), so the 128 B-frag VGPRs
// stay resident (budget 512).
// ---------------------------------------------------------------------------
__global__
__attribute__((amdgpu_flat_work_group_size(256, 256), amdgpu_waves_per_eu(1, 1)))
void scan_kernel(
    const float* __restrict__ Wf,
    const float* __restrict__ xgp,
    float* __restrict__ hs)
{
    const int tid  = threadIdx.x;
    const int lane = tid & 63;
    const int w    = tid >> 6;        // wave id 0..3
    const int col  = lane & 15;
    const int quad = lane >> 4;
    const int wbase = w * 32;
    const bool sel  = (lane >= 32);                 // p = sel
    const int jsel  = wbase + (sel ? 16 : 0) + col; // hidden index this lane updates

    __shared__ __align__(16) _Float16 h_lds[HH];

    // ---- one-time: B-fragments f32 -> f16 into named registers ----
    // row(nt) = (nt>>1)*128 + (nt&1)*16 + wbase + col ; elem off = kt*32 + quad*8
#define BLOAD(nt, kt) \
    half8 B##nt##_##kt; { \
        const float* p = Wf + \
            (((nt >> 1) * 128 + ((nt) & 1) * 16 + wbase + col) * HH) + (kt) * 32 + quad * 8; \
        float4 u = *(const float4*)p; \
        float4 v = *(const float4*)(p + 4); \
        B##nt##_##kt[0] = (_Float16)u.x; B##nt##_##kt[1] = (_Float16)u.y; \
        B##nt##_##kt[2] = (_Float16)u.z; B##nt##_##kt[3] = (_Float16)u.w; \
        B##nt##_##kt[4] = (_Float16)v.x; B##nt##_##kt[5] = (_Float16)v.y; \
        B##nt##_##kt[6] = (_Float16)v.z; B##nt##_##kt[7] = (_Float16)v.w; }
#define FOR_KT(X, nt) X(nt, 0) X(nt, 1) X(nt, 2) X(nt, 3)
#define FOR_NT(X) FOR_KT(X, 0) FOR_KT(X, 1) FOR_KT(X, 2) FOR_KT(X, 3) \
                  FOR_KT(X, 4) FOR_KT(X, 5) FOR_KT(X, 6) FOR_KT(X, 7)
    FOR_NT(BLOAD)

    // init h = 0, c = 0
    if (tid < HH) h_lds[tid] = (_Float16)0.f;
    float c = 0.f;

    // xg for t=0 (per-lane gate values at jsel)
    float xgi = xgp[0 * HH + jsel];
    float xgf = xgp[1 * HH + jsel];
    float xgg = xgp[2 * HH + jsel];
    float xgo = xgp[3 * HH + jsel];

    __syncthreads();

    const _Float16* hl = (const _Float16*)h_lds;
    const int aoff = quad * 8;

    for (int t = 0; t < TT; t++) {
        // ---- A-fragments: h replicated over rows ----
        half8 A0 = *(const half8*)(hl + 0 * 32 + aoff);
        half8 A1 = *(const half8*)(hl + 1 * 32 + aoff);
        half8 A2 = *(const half8*)(hl + 2 * 32 + aoff);
        half8 A3 = *(const half8*)(hl + 3 * 32 + aoff);
        __syncthreads();   // all reads of old h done before anyone writes

        // prefetch next step's xg row (vmem overlaps the MFMAs)
        const int tn = (t + 1 < TT) ? (t + 1) : (TT - 1);
        float xgi_n = xgp[tn * GG + 0 * HH + jsel];
        float xgf_n = xgp[tn * GG + 1 * HH + jsel];
        float xgg_n = xgp[tn * GG + 2 * HH + jsel];
        float xgo_n = xgp[tn * GG + 3 * HH + jsel];

        // ---- 32 MFMAs: 8 n-tiles x 4 k-tiles ----
        f32x4 C0 = {0.f,0.f,0.f,0.f}, C1 = {0.f,0.f,0.f,0.f};
        f32x4 C2 = {0.f,0.f,0.f,0.f}, C3 = {0.f,0.f,0.f,0.f};
        f32x4 C4 = {0.f,0.f,0.f,0.f}, C5 = {0.f,0.f,0.f,0.f};
        f32x4 C6 = {0.f,0.f,0.f,0.f}, C7 = {0.f,0.f,0.f,0.f};
#define MF(nt, kt) \
        C##nt = __builtin_amdgcn_mfma_f32_16x16x32_f16(A##kt, B##nt##_##kt, C##nt, 0, 0, 0);
#define MF_ALLNT(kt) MF(0, kt) MF(1, kt) MF(2, kt) MF(3, kt) \
                     MF(4, kt) MF(5, kt) MF(6, kt) MF(7, kt)
        MF_ALLNT(0) MF_ALLNT(1) MF_ALLNT(2) MF_ALLNT(3)

        // ---- epilogue: gates for hidden jsel (this lane) ----
        float pi = (sel ? C1[0] : C0[0]) + xgi;
        float pf = (sel ? C3[0] : C2[0]) + xgf;
        float pg = (sel ? C5[0] : C4[0]) + xgg;
        float po = (sel ? C7[0] : C6[0]) + xgo;

        float iv = sigmoid_fast(pi);
        float fv = sigmoid_fast(pf);
        float gv = tanh_fast(pg);
        float ov = sigmoid_fast(po);

        c = fv * c + iv * gv;
        float h = ov * tanh_fast(c);

        // one writer per hidden index: quad 0 (sel=0) and quad 3 (sel=1)
        if (quad == 0 || quad == 3) {
            h_lds[jsel] = (_Float16)h;
            if (t >= TT - BB) hs[(t - (TT - BB)) * HH + jsel] = h;
        }

        xgi = xgi_n; xgf = xgf_n; xgg = xgg_n; xgo = xgo_n;
        __syncthreads();   // new h visible before next A-read
    }
}

// ---------------------------------------------------------------------------
// Kernel 3: out[r,:] = W2 @ (W1 @ hs[r] + b1) + b2  (no activation in ref)
// ---------------------------------------------------------------------------
__global__ __launch_bounds__(128) void mlp_kernel(
    const float* __restrict__ hs,
    const float* __restrict__ W1,
    const float* __restrict__ b1,
    const float* __restrict__ W2,
    const float* __restrict__ b2,
    float* __restrict__ out)
{
    const int r = blockIdx.x;
    const int j = threadIdx.x;

    __shared__ __align__(16) float hsh[HH];
    __shared__ __align__(16) float z[HH];

    hsh[j] = hs[r * HH + j];
    __syncthreads();

    {
        const float4* __restrict__ wrow = (const float4*)(W1 + j * HH);
        const float4* __restrict__ hv   = (const float4*)hsh;
        float acc = b1[j];
#pragma unroll
        for (int i = 0; i < 32; i++) {
            float4 ww = wrow[i], h = hv[i];
            acc += ww.x * h.x + ww.y * h.y + ww.z * h.z + ww.w * h.w;
        }
        z[j] = acc;
    }
    __syncthreads();

    if (j < OO) {
        const float4* __restrict__ wrow = (const float4*)(W2 + j * HH);
        const float4* __restrict__ zv   = (const float4*)z;
        float acc = b2[j];
#pragma unroll
        for (int i = 0; i < 32; i++) {
            float4 ww = wrow[i], zz = zv[i];
            acc += ww.x * zz.x + ww.y * zz.y + ww.z * zz.z + ww.w * zz.w;
        }
        out[r * OO + j] = acc;
    }
}

// ---------------------------------------------------------------------------
// Launch. Inputs: 0:x 1:W_ih 2:W_hh 3:b_ih 4:b_hh 5:W1 6:b1 7:W2 8:b2
// ws: xg (1 MB) | hs (128 KB)
// ---------------------------------------------------------------------------
extern "C" void kernel_launch(void* const* d_in, const int* in_sizes, int n_in,
                              void* d_out, int out_size, void* d_ws, size_t ws_size,
                              hipStream_t stream) {
    const float* x    = (const float*)d_in[0];
    const float* W_ih = (const float*)d_in[1];
    const float* W_hh = (const float*)d_in[2];
    const float* b_ih = (const float*)d_in[3];
    const float* b_hh = (const float*)d_in[4];
    const float* W1   = (const float*)d_in[5];
    const float* b1   = (const float*)d_in[6];
    const float* W2   = (const float*)d_in[7];
    const float* b2   = (const float*)d_in[8];
    float* out = (float*)d_out;

    float* xg = (float*)d_ws;            // T*4H = 262144 f32
    float* hs = xg + TT * GG;            // 256*H = 32768 f32

    xg_kernel<<<TT, 512, 0, stream>>>(x, W_ih, b_ih, b_hh, xg);
    scan_kernel<<<1, 256, 0, stream>>>(W_hh, xg, hs);
    mlp_kernel<<<BB, 128, 0, stream>>>(hs, W1, b1, W2, b2, out);
}

// Round 5
// 421.500 us; speedup vs baseline: 1.0273x; 1.0273x over previous
//
#include <hip/hip_runtime.h>
#include <math.h>

// Problem constants (fixed by the reference)
#define BB 256
#define TT 512
#define DD 128
#define HH 128
#define GG 512   // 4*H
#define OO 64

typedef _Float16 half8 __attribute__((ext_vector_type(8)));
typedef float    f32x4 __attribute__((ext_vector_type(4)));

// ---------------------------------------------------------------------------
// Fast activations (fp32; threshold 5.6e-3, plenty of headroom)
// ---------------------------------------------------------------------------
__device__ __forceinline__ float sigmoid_fast(float x) {
    return 1.0f / (1.0f + __expf(-x));
}
__device__ __forceinline__ float tanh_fast(float x) {
    float ax = fabsf(x);
    float e = __expf(2.0f * ax);
    float t = 1.0f - 2.0f / (e + 1.0f);
    return copysignf(t, x);
}

// ---------------------------------------------------------------------------
// Kernel 1: xg[t][g] = dot(x[255,t,:], W_ih[g,:]) + b_ih[g] + b_hh[g]
// Only batch 255 matters: y.reshape(T,B,O)[-1] -> flat rows (b=255, t>=256),
// and b=255's scan needs all t. grid = T, block = 512.
// ---------------------------------------------------------------------------
__global__ __launch_bounds__(512) void xg_kernel(
    const float* __restrict__ x,
    const float* __restrict__ W_ih,
    const float* __restrict__ b_ih,
    const float* __restrict__ b_hh,
    float* __restrict__ xg)
{
    const int t = blockIdx.x;
    const int g = threadIdx.x;

    __shared__ __align__(16) float xs[DD];
    if (g < DD) xs[g] = x[(255 * TT + t) * DD + g];
    __syncthreads();

    const float4* __restrict__ wrow = (const float4*)(W_ih + g * DD);
    const float4* __restrict__ xv   = (const float4*)xs;

    float a0 = 0.f, a1 = 0.f, a2 = 0.f, a3 = 0.f;
#pragma unroll
    for (int i = 0; i < DD / 4; i += 4) {
        float4 w0 = wrow[i + 0], w1 = wrow[i + 1], w2 = wrow[i + 2], w3 = wrow[i + 3];
        float4 h0 = xv[i + 0],  h1 = xv[i + 1],  h2 = xv[i + 2],  h3 = xv[i + 3];
        a0 += w0.x * h0.x + w0.y * h0.y + w0.z * h0.z + w0.w * h0.w;
        a1 += w1.x * h1.x + w1.y * h1.y + w1.z * h1.z + w1.w * h1.w;
        a2 += w2.x * h2.x + w2.y * h2.y + w2.z * h2.z + w2.w * h2.w;
        a3 += w3.x * h3.x + w3.y * h3.y + w3.z * h3.z + w3.w * h3.w;
    }
    xg[t * GG + g] = (a0 + a1) + (a2 + a3) + b_ih[g] + b_hh[g];
}

// ---------------------------------------------------------------------------
// Kernel 2: MFMA LSTM scan (batch 255). 1 block, 256 threads = 4 waves.
//
// pre[g] = xg[t][g] + h . W_hh[g,:] via v_mfma_f32_16x16x32_f16.
//   - A-frag: h replicated across all 16 rows (every C row = the matvec).
//   - B-frag: wave w owns hidden slice [32w,32w+32) for ALL 4 gate types ->
//     i,f,g,o for hidden j land in the same lane; update is cross-lane-free.
//
// AGPR PIN (rounds 2-4 failure): the compiler kept sinking the weight
// load+cvt into the loop (round-4 counters: ~300 VALU instr/step = 32 frags
// x 8 cvt re-run per step; 256 KB/step L1/L2 traffic = the 1450-cyc step).
// A volatile empty asm with "+a" constraints INSIDE the loop redefines the
// fragments each iteration: remat is now illegal and the values must live in
// AGPRs (128 AGPRs; gfx950 MFMA reads B from AGPR natively, budget 512/wave
// at waves_per_eu(1,1)).
//
// Single barrier per step: double-buffered h_lds (read buf[p], write buf[1-p];
// reads of a buffer and the next write to it are separated by the barrier).
// ---------------------------------------------------------------------------
__global__
__attribute__((amdgpu_flat_work_group_size(256, 256), amdgpu_waves_per_eu(1, 1)))
void scan_kernel(
    const float* __restrict__ Wf,
    const float* __restrict__ xgp,
    float* __restrict__ hs)
{
    const int tid  = threadIdx.x;
    const int lane = tid & 63;
    const int w    = tid >> 6;        // wave id 0..3
    const int col  = lane & 15;
    const int quad = lane >> 4;
    const int wbase = w * 32;
    const bool sel  = (lane >= 32);                 // p = sel
    const int jsel  = wbase + (sel ? 16 : 0) + col; // hidden index this lane updates

    __shared__ __align__(16) _Float16 h_lds[2][HH];

    // ---- one-time: B-fragments f32 -> f16 into registers ----
    // row(nt) = (nt>>1)*128 + (nt&1)*16 + wbase + col ; elem off = kt*32 + quad*8
#define BLOAD(nt, kt) \
    half8 B##nt##_##kt; { \
        const float* p = Wf + \
            (((nt >> 1) * 128 + ((nt) & 1) * 16 + wbase + col) * HH) + (kt) * 32 + quad * 8; \
        float4 u = *(const float4*)p; \
        float4 v = *(const float4*)(p + 4); \
        B##nt##_##kt[0] = (_Float16)u.x; B##nt##_##kt[1] = (_Float16)u.y; \
        B##nt##_##kt[2] = (_Float16)u.z; B##nt##_##kt[3] = (_Float16)u.w; \
        B##nt##_##kt[4] = (_Float16)v.x; B##nt##_##kt[5] = (_Float16)v.y; \
        B##nt##_##kt[6] = (_Float16)v.z; B##nt##_##kt[7] = (_Float16)v.w; }
#define FOR_KT(X, nt) X(nt, 0) X(nt, 1) X(nt, 2) X(nt, 3)
#define FOR_NT(X) FOR_KT(X, 0) FOR_KT(X, 1) FOR_KT(X, 2) FOR_KT(X, 3) \
                  FOR_KT(X, 4) FOR_KT(X, 5) FOR_KT(X, 6) FOR_KT(X, 7)
    FOR_NT(BLOAD)

    // init h = 0, c = 0
    if (tid < HH) h_lds[0][tid] = (_Float16)0.f;
    float c = 0.f;

    // xg for t=0 (per-lane gate values at jsel)
    float xgi = xgp[0 * HH + jsel];
    float xgf = xgp[1 * HH + jsel];
    float xgg = xgp[2 * HH + jsel];
    float xgo = xgp[3 * HH + jsel];

    __syncthreads();

    const int aoff = quad * 8;
    int p = 0;

    for (int t = 0; t < TT; t++) {
        // Pin all 32 B-fragments into AGPRs, redefined per iteration ->
        // the allocator cannot remat/sink the loads+cvts into the loop.
        asm volatile("" : "+a"(B0_0), "+a"(B0_1), "+a"(B0_2), "+a"(B0_3),
                          "+a"(B1_0), "+a"(B1_1), "+a"(B1_2), "+a"(B1_3),
                          "+a"(B2_0), "+a"(B2_1), "+a"(B2_2), "+a"(B2_3),
                          "+a"(B3_0), "+a"(B3_1), "+a"(B3_2), "+a"(B3_3));
        asm volatile("" : "+a"(B4_0), "+a"(B4_1), "+a"(B4_2), "+a"(B4_3),
                          "+a"(B5_0), "+a"(B5_1), "+a"(B5_2), "+a"(B5_3),
                          "+a"(B6_0), "+a"(B6_1), "+a"(B6_2), "+a"(B6_3),
                          "+a"(B7_0), "+a"(B7_1), "+a"(B7_2), "+a"(B7_3));

        // ---- A-fragments: h replicated over rows (read current buffer) ----
        const _Float16* hl = h_lds[p];
        half8 A0 = *(const half8*)(hl + 0 * 32 + aoff);
        half8 A1 = *(const half8*)(hl + 1 * 32 + aoff);
        half8 A2 = *(const half8*)(hl + 2 * 32 + aoff);
        half8 A3 = *(const half8*)(hl + 3 * 32 + aoff);

        // prefetch next step's xg row (vmem overlaps the MFMAs)
        const int tn = (t + 1 < TT) ? (t + 1) : (TT - 1);
        float xgi_n = xgp[tn * GG + 0 * HH + jsel];
        float xgf_n = xgp[tn * GG + 1 * HH + jsel];
        float xgg_n = xgp[tn * GG + 2 * HH + jsel];
        float xgo_n = xgp[tn * GG + 3 * HH + jsel];

        // ---- 32 MFMAs: 8 n-tiles x 4 k-tiles ----
        f32x4 C0 = {0.f,0.f,0.f,0.f}, C1 = {0.f,0.f,0.f,0.f};
        f32x4 C2 = {0.f,0.f,0.f,0.f}, C3 = {0.f,0.f,0.f,0.f};
        f32x4 C4 = {0.f,0.f,0.f,0.f}, C5 = {0.f,0.f,0.f,0.f};
        f32x4 C6 = {0.f,0.f,0.f,0.f}, C7 = {0.f,0.f,0.f,0.f};
#define MF(nt, kt) \
        C##nt = __builtin_amdgcn_mfma_f32_16x16x32_f16(A##kt, B##nt##_##kt, C##nt, 0, 0, 0);
#define MF_ALLNT(kt) MF(0, kt) MF(1, kt) MF(2, kt) MF(3, kt) \
                     MF(4, kt) MF(5, kt) MF(6, kt) MF(7, kt)
        MF_ALLNT(0) MF_ALLNT(1) MF_ALLNT(2) MF_ALLNT(3)

        // ---- epilogue: gates for hidden jsel (this lane) ----
        float pi = (sel ? C1[0] : C0[0]) + xgi;
        float pf = (sel ? C3[0] : C2[0]) + xgf;
        float pg = (sel ? C5[0] : C4[0]) + xgg;
        float po = (sel ? C7[0] : C6[0]) + xgo;

        float iv = sigmoid_fast(pi);
        float fv = sigmoid_fast(pf);
        float gv = tanh_fast(pg);
        float ov = sigmoid_fast(po);

        c = fv * c + iv * gv;
        float h = ov * tanh_fast(c);

        // one writer per hidden index (quads 0 and 3); write NEXT buffer
        if (quad == 0 || quad == 3) {
            h_lds[1 - p][jsel] = (_Float16)h;
            if (t >= TT - BB) hs[(t - (TT - BB)) * HH + jsel] = h;
        }

        xgi = xgi_n; xgf = xgf_n; xgg = xgg_n; xgo = xgo_n;
        p ^= 1;
        __syncthreads();   // writes visible; old-buffer reads done before reuse
    }
}

// ---------------------------------------------------------------------------
// Kernel 3: out[r,:] = W2 @ (W1 @ hs[r] + b1) + b2  (no activation in ref)
// ---------------------------------------------------------------------------
__global__ __launch_bounds__(128) void mlp_kernel(
    const float* __restrict__ hs,
    const float* __restrict__ W1,
    const float* __restrict__ b1,
    const float* __restrict__ W2,
    const float* __restrict__ b2,
    float* __restrict__ out)
{
    const int r = blockIdx.x;
    const int j = threadIdx.x;

    __shared__ __align__(16) float hsh[HH];
    __shared__ __align__(16) float z[HH];

    hsh[j] = hs[r * HH + j];
    __syncthreads();

    {
        const float4* __restrict__ wrow = (const float4*)(W1 + j * HH);
        const float4* __restrict__ hv   = (const float4*)hsh;
        float acc = b1[j];
#pragma unroll
        for (int i = 0; i < 32; i++) {
            float4 ww = wrow[i], h = hv[i];
            acc += ww.x * h.x + ww.y * h.y + ww.z * h.z + ww.w * h.w;
        }
        z[j] = acc;
    }
    __syncthreads();

    if (j < OO) {
        const float4* __restrict__ wrow = (const float4*)(W2 + j * HH);
        const float4* __restrict__ zv   = (const float4*)z;
        float acc = b2[j];
#pragma unroll
        for (int i = 0; i < 32; i++) {
            float4 ww = wrow[i], zz = zv[i];
            acc += ww.x * zz.x + ww.y * zz.y + ww.z * zz.z + ww.w * zz.w;
        }
        out[r * OO + j] = acc;
    }
}

// ---------------------------------------------------------------------------
// Launch. Inputs: 0:x 1:W_ih 2:W_hh 3:b_ih 4:b_hh 5:W1 6:b1 7:W2 8:b2
// ws: xg (1 MB) | hs (128 KB)
// ---------------------------------------------------------------------------
extern "C" void kernel_launch(void* const* d_in, const int* in_sizes, int n_in,
                              void* d_out, int out_size, void* d_ws, size_t ws_size,
                              hipStream_t stream) {
    const float* x    = (const float*)d_in[0];
    const float* W_ih = (const float*)d_in[1];
    const float* W_hh = (const float*)d_in[2];
    const float* b_ih = (const float*)d_in[3];
    const float* b_hh = (const float*)d_in[4];
    const float* W1   = (const float*)d_in[5];
    const float* b1   = (const float*)d_in[6];
    const float* W2   = (const float*)d_in[7];
    const float* b2   = (const float*)d_in[8];
    float* out = (float*)d_out;

    float* xg = (float*)d_ws;            // T*4H = 262144 f32
    float* hs = xg + TT * GG;            // 256*H = 32768 f32

    xg_kernel<<<TT, 512, 0, stream>>>(x, W_ih, b_ih, b_hh, xg);
    scan_kernel<<<1, 256, 0, stream>>>(W_hh, xg, hs);
    mlp_kernel<<<BB, 128, 0, stream>>>(hs, W1, b1, W2, b2, out);
}